// Round 8
// baseline (111.586 us; speedup 1.0000x reference)
//
#include <hip/hip_runtime.h>
#include <hip/hip_bf16.h>

#define H_IMG 720
#define W_IMG 1280
#define NPIX (H_IMG * W_IMG)

typedef __attribute__((ext_vector_type(4))) float f32x4;
typedef __attribute__((ext_vector_type(8))) short short8;
typedef __attribute__((ext_vector_type(4))) short short4v;

// ---- workspace layout (bytes) ----
// wpack: 14 hi-frags * 64 lanes * 16B
#define WPACK_BYTES (14 * 64 * 16)
#define GP0_OFF WPACK_BYTES
#define GP0_N (16 * 16 * 8 * 8)   // [y][x][z][c] f32
#define GP1_OFF (GP0_OFF + GP0_N * 4)
#define GP1_N (12 * 12 * 8 * 8)
#define GP2_OFF (GP1_OFF + GP1_N * 4)
#define GP2_N (8 * 8 * 4 * 8)

#define XSTR 36  // ushorts per staging row: 32 payload + 4 pad

__device__ __forceinline__ uint pkbf(float a, float b) {
  // packed f32x2 -> bf16x2 (v_cvt_pk_bf16_f32), RNE
  float2 t2 = make_float2(a, b);
  __hip_bfloat162 t = __float22bfloat162_rn(t2);
  uint u;
  __builtin_memcpy(&u, &t, 4);
  return u;
}

__device__ __forceinline__ float tanh5(float x) {
  // tanh(x) = 1 - 2/(e^{2x}+1); graceful at +-inf, no clamp needed.
  float e2 = __builtin_amdgcn_exp2f(x * 2.885390081777927f);  // e^{2x} via v_exp_f32
  return fmaf(-2.f, __builtin_amdgcn_rcpf(e2 + 1.f), 1.f);
}

// ================= prep kernel =================
__global__ __launch_bounds__(256) void prep_kernel(
    const float* __restrict__ g0, const float* __restrict__ g1, const float* __restrict__ g2,
    const float* __restrict__ w1, const float* __restrict__ w2, const float* __restrict__ w3,
    const int* __restrict__ cam, void* __restrict__ ws) {
  ushort* wpack = (ushort*)ws;
  float* gp0 = (float*)((char*)ws + GP0_OFF);
  float* gp1 = (float*)((char*)ws + GP1_OFF);
  float* gp2 = (float*)((char*)ws + GP2_OFF);
  const int ci = cam[0];
  const int tid = blockIdx.x * 256 + threadIdx.x;
  const int nth = gridDim.x * 256;

  // grids -> [y][x][z][c] f32, selected view only
  for (int e = tid; e < GP0_N; e += nth) {
    int c = e & 7; int t = e >> 3; int z = t & 7; t >>= 3; int x = t & 15; int y = t >> 4;
    gp0[e] = g0[ci * GP0_N + ((c * 8 + z) * 16 + y) * 16 + x];
  }
  for (int e = tid; e < GP1_N; e += nth) {
    int c = e & 7; int t = e >> 3; int z = t & 7; t >>= 3; int x = t % 12; int y = t / 12;
    gp1[e] = g1[ci * GP1_N + ((c * 8 + z) * 12 + y) * 12 + x];
  }
  for (int e = tid; e < GP2_N; e += nth) {
    int c = e & 7; int t = e >> 3; int z = t & 3; t >>= 2; int x = t & 7; int y = t >> 3;
    gp2[e] = g2[ci * GP2_N + ((c * 4 + z) * 8 + y) * 8 + x];
  }

  // weights -> per-lane A-fragments (A = W^T), hi bf16 only.
  // frag f: 0..3 = L1 (mt), 4..11 = L2 (4+ks*4+mt), 12..13 = L3 (ks).
  for (int fl = tid; fl < 14 * 64; fl += nth) {
    int f = fl >> 6, lane = fl & 63;
    int g = lane >> 4, r = lane & 15;
    ushort* dh = wpack + fl * 8;
#pragma unroll
    for (int j = 0; j < 8; ++j) {
      float v = 0.f;
      if (f < 4) {
        int k = 8 * g + j, n = r + 16 * f;
        if (k < 24) v = w1[k * 64 + n];
      } else if (f < 12) {
        int q = f - 4, ks = q >> 2, mt = q & 3;
        v = w2[(8 * g + j + 32 * ks) * 64 + (r + 16 * mt)];
      } else {
        int ks = f - 12;
        if (r < 12) v = w3[(8 * g + j + 32 * ks) * 12 + r];
      }
      __hip_bfloat16 bh = __float2bfloat16(v);
      dh[j] = *(ushort*)&bh;
    }
  }
}

// ================= slicing =================
template <int WG, int HG, int LG>
__device__ __forceinline__ void slice_pack(const float* __restrict__ gp,
                                           int row, int col, float gray,
                                           float* __restrict__ out8) {
  float x = (float)col * ((float)(WG - 1) / (float)(W_IMG - 1));
  float y = (float)row * ((float)(HG - 1) / (float)(H_IMG - 1));
  float z = gray * (float)(LG - 1);
  int x0 = (int)x, y0 = (int)y, z0 = (int)z;
  int x1 = min(x0 + 1, WG - 1), y1 = min(y0 + 1, HG - 1), z1 = min(z0 + 1, LG - 1);
  float wx = x - (float)x0, wy = y - (float)y0, wz = z - (float)z0;

  const float* p00 = gp + ((y0 * WG + x0) * LG) * 8;
  const float* p01 = gp + ((y0 * WG + x1) * LG) * 8;
  const float* p10 = gp + ((y1 * WG + x0) * LG) * 8;
  const float* p11 = gp + ((y1 * WG + x1) * LG) * 8;

  f32x4 s00a = *(const f32x4*)(p00 + z0 * 8), s00b = *(const f32x4*)(p00 + z0 * 8 + 4);
  f32x4 s01a = *(const f32x4*)(p01 + z0 * 8), s01b = *(const f32x4*)(p01 + z0 * 8 + 4);
  f32x4 s10a = *(const f32x4*)(p10 + z0 * 8), s10b = *(const f32x4*)(p10 + z0 * 8 + 4);
  f32x4 s11a = *(const f32x4*)(p11 + z0 * 8), s11b = *(const f32x4*)(p11 + z0 * 8 + 4);
  f32x4 t00a = *(const f32x4*)(p00 + z1 * 8), t00b = *(const f32x4*)(p00 + z1 * 8 + 4);
  f32x4 t01a = *(const f32x4*)(p01 + z1 * 8), t01b = *(const f32x4*)(p01 + z1 * 8 + 4);
  f32x4 t10a = *(const f32x4*)(p10 + z1 * 8), t10b = *(const f32x4*)(p10 + z1 * 8 + 4);
  f32x4 t11a = *(const f32x4*)(p11 + z1 * 8), t11b = *(const f32x4*)(p11 + z1 * 8 + 4);

#pragma unroll
  for (int c = 0; c < 8; ++c) {
    float c00 = (c < 4) ? s00a[c & 3] : s00b[c & 3];
    float c01 = (c < 4) ? s01a[c & 3] : s01b[c & 3];
    float c10 = (c < 4) ? s10a[c & 3] : s10b[c & 3];
    float c11 = (c < 4) ? s11a[c & 3] : s11b[c & 3];
    float d00 = (c < 4) ? t00a[c & 3] : t00b[c & 3];
    float d01 = (c < 4) ? t01a[c & 3] : t01b[c & 3];
    float d10 = (c < 4) ? t10a[c & 3] : t10b[c & 3];
    float d11 = (c < 4) ? t11a[c & 3] : t11b[c & 3];
    float h0 = fmaf(wx, c01 - c00, c00);
    float h1 = fmaf(wx, c11 - c10, c10);
    float v0 = fmaf(wy, h1 - h0, h0);
    float g0v = fmaf(wx, d01 - d00, d00);
    float g1v = fmaf(wx, d11 - d10, d10);
    float v1 = fmaf(wy, g1v - g0v, g0v);
    out8[c] = fmaf(wz, v1 - v0, v0);
  }
}

// ================= main kernel =================
// 1-wave workgroups (waves are fully independent: wave-private LDS, no barriers).
// Block=64 lets the SPI backfill residency at wave granularity instead of
// 4-wave/18KB block granularity -- attacks the measured 32% occupancy.
// launch_bounds(64,7): VGPR cap 73 (natural usage 64, r6/r7 measured).
__global__ __launch_bounds__(64, 7) void msnbat_kernel(
    const float* __restrict__ rgb, const void* __restrict__ ws, float* __restrict__ out) {
  __shared__ ushort W[64 * XSTR];  // 4608 B/block
  uint* Wu = (uint*)W;

  const short8* wp = (const short8*)ws;  // frag f, lane l -> wp[f*64+l]
  const float* gp0 = (const float*)((const char*)ws + GP0_OFF);
  const float* gp1 = (const float*)((const char*)ws + GP1_OFF);
  const float* gp2 = (const float*)((const char*)ws + GP2_OFF);

  const int lane = threadIdx.x;
  const int g = lane >> 4, r = lane & 15;
  const int pixbase = blockIdx.x * 64;
  const int p = pixbase + lane;
  const int row = p / W_IMG;
  const int col = p - row * W_IMG;

  const float rr = rgb[p * 3 + 0], gg = rgb[p * 3 + 1], bb = rgb[p * 3 + 2];
  const float gray = fminf(fmaxf(rr * 0.299f + gg * 0.587f + bb * 0.114f, 0.f), 1.f);

  // ---- slice 24 features (lane = its own pixel) ----
  float f[24];
  slice_pack<16, 16, 8>(gp0, row, col, gray, f);
  slice_pack<12, 12, 8>(gp1, row, col, gray, f + 8);
  slice_pack<8, 8, 4>(gp2, row, col, gray, f + 16);

  // ---- stage X: row = pixel(lane), cols 0..23 bf16 feats (24..31 unwritten) ----
  {
    const int ub = lane * 18;  // uint base of this row
#pragma unroll
    for (int i = 0; i < 6; ++i) {
      uint2 v = make_uint2(pkbf(f[4 * i + 0], f[4 * i + 1]), pkbf(f[4 * i + 2], f[4 * i + 3]));
      *(uint2*)&Wu[ub + 2 * i] = v;
    }
  }

  const short8 zero8 = (short8){0, 0, 0, 0, 0, 0, 0, 0};

  // ---- B1 frags: lane(g,r) reads X[pixel r+16nt][feat 8g+j]; g==3 = K-pad -> 0 ----
  short8 B1[4];
#pragma unroll
  for (int nt = 0; nt < 4; ++nt) {
    short4v lo = *(short4v*)&W[(r + 16 * nt) * XSTR + 8 * g];
    short4v hi = *(short4v*)&W[(r + 16 * nt) * XSTR + 8 * g + 4];
    short8 v = __builtin_shufflevector(lo, hi, 0, 1, 2, 3, 4, 5, 6, 7);
    B1[nt] = (g < 3) ? v : zero8;
  }

  // ---- L1 (24->64) in mt-halves; stage tanh(H1) halves; build B2 frags ----
  short8 B2[2][4];
#pragma unroll
  for (int half = 0; half < 2; ++half) {
#pragma unroll
    for (int mtl = 0; mtl < 2; ++mtl) {
      const int mt = 2 * half + mtl;
      short8 A = wp[mt * 64 + lane];
      f32x4 a[4];
#pragma unroll
      for (int nt = 0; nt < 4; ++nt) a[nt] = (f32x4){0.f, 0.f, 0.f, 0.f};
#pragma unroll
      for (int nt = 0; nt < 4; ++nt)
        a[nt] = __builtin_amdgcn_mfma_f32_16x16x32_bf16(A, B1[nt], a[nt], 0, 0, 0);
#pragma unroll
      for (int nt = 0; nt < 4; ++nt) {
        uint2 v = make_uint2(pkbf(tanh5(a[nt][0]), tanh5(a[nt][1])),
                             pkbf(tanh5(a[nt][2]), tanh5(a[nt][3])));
        *(uint2*)&Wu[(16 * nt + r) * 18 + 8 * mtl + 2 * g] = v;
      }
    }
#pragma unroll
    for (int nt = 0; nt < 4; ++nt) {
      short4v lo = *(short4v*)&W[(16 * nt + r) * XSTR + 8 * g];
      short4v hi = *(short4v*)&W[(16 * nt + r) * XSTR + 8 * g + 4];
      B2[half][nt] = __builtin_shufflevector(lo, hi, 0, 1, 2, 3, 4, 5, 6, 7);
    }
  }

  // ---- L2 (64->64) in mt-halves; stage tanh(H2) halves; build B3 frags ----
  short8 B3[2][4];
#pragma unroll
  for (int half = 0; half < 2; ++half) {
#pragma unroll
    for (int mtl = 0; mtl < 2; ++mtl) {
      const int mt = 2 * half + mtl;
      short8 A0 = wp[(4 + mt) * 64 + lane];  // ks=0
      short8 A1 = wp[(8 + mt) * 64 + lane];  // ks=1
      f32x4 a[4];
#pragma unroll
      for (int nt = 0; nt < 4; ++nt) a[nt] = (f32x4){0.f, 0.f, 0.f, 0.f};
#pragma unroll
      for (int nt = 0; nt < 4; ++nt)
        a[nt] = __builtin_amdgcn_mfma_f32_16x16x32_bf16(A0, B2[0][nt], a[nt], 0, 0, 0);
#pragma unroll
      for (int nt = 0; nt < 4; ++nt)
        a[nt] = __builtin_amdgcn_mfma_f32_16x16x32_bf16(A1, B2[1][nt], a[nt], 0, 0, 0);
#pragma unroll
      for (int nt = 0; nt < 4; ++nt) {
        uint2 v = make_uint2(pkbf(tanh5(a[nt][0]), tanh5(a[nt][1])),
                             pkbf(tanh5(a[nt][2]), tanh5(a[nt][3])));
        *(uint2*)&Wu[(16 * nt + r) * 18 + 8 * mtl + 2 * g] = v;
      }
    }
#pragma unroll
    for (int nt = 0; nt < 4; ++nt) {
      short4v lo = *(short4v*)&W[(16 * nt + r) * XSTR + 8 * g];
      short4v hi = *(short4v*)&W[(16 * nt + r) * XSTR + 8 * g + 4];
      B3[half][nt] = __builtin_shufflevector(lo, hi, 0, 1, 2, 3, 4, 5, 6, 7);
    }
  }

  // ---- L3 (64->12): M=16 (12 valid), K=64 ----
  f32x4 acc3[4];
#pragma unroll
  for (int nt = 0; nt < 4; ++nt) acc3[nt] = (f32x4){0.f, 0.f, 0.f, 0.f};
  {
    short8 A0 = wp[12 * 64 + lane];
    short8 A1 = wp[13 * 64 + lane];
#pragma unroll
    for (int nt = 0; nt < 4; ++nt)
      acc3[nt] = __builtin_amdgcn_mfma_f32_16x16x32_bf16(A0, B3[0][nt], acc3[nt], 0, 0, 0);
#pragma unroll
    for (int nt = 0; nt < 4; ++nt)
      acc3[nt] = __builtin_amdgcn_mfma_f32_16x16x32_bf16(A1, B3[1][nt], acc3[nt], 0, 0, 0);
  }

  // ---- store: lane(g<3, r) holds channels 4g..4g+3 of pixel 16nt+r ----
  if (g < 3) {
#pragma unroll
    for (int nt = 0; nt < 4; ++nt) {
      int pix = pixbase + 16 * nt + r;
      *(f32x4*)(out + pix * 12 + 4 * g) = acc3[nt];
    }
  }
}

extern "C" void kernel_launch(void* const* d_in, const int* in_sizes, int n_in,
                              void* d_out, int out_size, void* d_ws, size_t ws_size,
                              hipStream_t stream) {
  const float* rgb = (const float*)d_in[0];
  const float* g0 = (const float*)d_in[1];
  const float* g1 = (const float*)d_in[2];
  const float* g2 = (const float*)d_in[3];
  const float* w1 = (const float*)d_in[4];
  const float* w2 = (const float*)d_in[5];
  const float* w3 = (const float*)d_in[6];
  const int* cam = (const int*)d_in[7];
  float* out = (float*)d_out;

  hipLaunchKernelGGL(prep_kernel, dim3(64), dim3(256), 0, stream,
                     g0, g1, g2, w1, w2, w3, cam, d_ws);
  hipLaunchKernelGGL(msnbat_kernel, dim3(NPIX / 64), dim3(64), 0, stream,
                     rgb, d_ws, out);
}

// Round 9
// 58.481 us; speedup vs baseline: 1.9081x; 1.9081x over previous
//
#include <hip/hip_runtime.h>
#include <hip/hip_bf16.h>

#define H_IMG 720
#define W_IMG 1280
#define NPIX (H_IMG * W_IMG)

typedef __attribute__((ext_vector_type(4))) float f32x4;
typedef __attribute__((ext_vector_type(8))) short short8;
typedef __attribute__((ext_vector_type(4))) short short4v;

// ---- workspace layout (bytes) ----
// wpack: 14 hi-frags * 64 lanes * 16B
#define WPACK_BYTES (14 * 64 * 16)
#define GP0_OFF WPACK_BYTES
#define GP0_N (16 * 16 * 8 * 8)   // [y][x][z][c] f32
#define GP1_OFF (GP0_OFF + GP0_N * 4)
#define GP1_N (12 * 12 * 8 * 8)
#define GP2_OFF (GP1_OFF + GP1_N * 4)
#define GP2_N (8 * 8 * 4 * 8)

#define XSTR 36  // ushorts per staging row: 32 payload + 4 pad

__device__ __forceinline__ uint pkbf(float a, float b) {
  // packed f32x2 -> bf16x2 (v_cvt_pk_bf16_f32), RNE
  float2 t2 = make_float2(a, b);
  __hip_bfloat162 t = __float22bfloat162_rn(t2);
  uint u;
  __builtin_memcpy(&u, &t, 4);
  return u;
}

__device__ __forceinline__ float tanh5(float x) {
  // tanh(x) = 1 - 2/(e^{2x}+1); graceful at +-inf, no clamp needed.
  float e2 = __builtin_amdgcn_exp2f(x * 2.885390081777927f);  // e^{2x} via v_exp_f32
  return fmaf(-2.f, __builtin_amdgcn_rcpf(e2 + 1.f), 1.f);
}

// ================= prep kernel =================
__global__ __launch_bounds__(256) void prep_kernel(
    const float* __restrict__ g0, const float* __restrict__ g1, const float* __restrict__ g2,
    const float* __restrict__ w1, const float* __restrict__ w2, const float* __restrict__ w3,
    const int* __restrict__ cam, void* __restrict__ ws) {
  ushort* wpack = (ushort*)ws;
  float* gp0 = (float*)((char*)ws + GP0_OFF);
  float* gp1 = (float*)((char*)ws + GP1_OFF);
  float* gp2 = (float*)((char*)ws + GP2_OFF);
  const int ci = cam[0];
  const int tid = blockIdx.x * 256 + threadIdx.x;
  const int nth = gridDim.x * 256;

  // grids -> [y][x][z][c] f32, selected view only
  for (int e = tid; e < GP0_N; e += nth) {
    int c = e & 7; int t = e >> 3; int z = t & 7; t >>= 3; int x = t & 15; int y = t >> 4;
    gp0[e] = g0[ci * GP0_N + ((c * 8 + z) * 16 + y) * 16 + x];
  }
  for (int e = tid; e < GP1_N; e += nth) {
    int c = e & 7; int t = e >> 3; int z = t & 7; t >>= 3; int x = t % 12; int y = t / 12;
    gp1[e] = g1[ci * GP1_N + ((c * 8 + z) * 12 + y) * 12 + x];
  }
  for (int e = tid; e < GP2_N; e += nth) {
    int c = e & 7; int t = e >> 3; int z = t & 3; t >>= 2; int x = t & 7; int y = t >> 3;
    gp2[e] = g2[ci * GP2_N + ((c * 4 + z) * 8 + y) * 8 + x];
  }

  // weights -> per-lane A-fragments (A = W^T), hi bf16 only.
  // frag f: 0..3 = L1 (mt), 4..11 = L2 (4+ks*4+mt), 12..13 = L3 (ks).
  for (int fl = tid; fl < 14 * 64; fl += nth) {
    int f = fl >> 6, lane = fl & 63;
    int g = lane >> 4, r = lane & 15;
    ushort* dh = wpack + fl * 8;
#pragma unroll
    for (int j = 0; j < 8; ++j) {
      float v = 0.f;
      if (f < 4) {
        int k = 8 * g + j, n = r + 16 * f;
        if (k < 24) v = w1[k * 64 + n];
      } else if (f < 12) {
        int q = f - 4, ks = q >> 2, mt = q & 3;
        v = w2[(8 * g + j + 32 * ks) * 64 + (r + 16 * mt)];
      } else {
        int ks = f - 12;
        if (r < 12) v = w3[(8 * g + j + 32 * ks) * 12 + r];
      }
      __hip_bfloat16 bh = __float2bfloat16(v);
      dh[j] = *(ushort*)&bh;
    }
  }
}

// ================= slicing =================
template <int WG, int HG, int LG>
__device__ __forceinline__ void slice_pack(const float* __restrict__ gp,
                                           int row, int col, float gray,
                                           float* __restrict__ out8) {
  float x = (float)col * ((float)(WG - 1) / (float)(W_IMG - 1));
  float y = (float)row * ((float)(HG - 1) / (float)(H_IMG - 1));
  float z = gray * (float)(LG - 1);
  int x0 = (int)x, y0 = (int)y, z0 = (int)z;
  int x1 = min(x0 + 1, WG - 1), y1 = min(y0 + 1, HG - 1), z1 = min(z0 + 1, LG - 1);
  float wx = x - (float)x0, wy = y - (float)y0, wz = z - (float)z0;

  const float* p00 = gp + ((y0 * WG + x0) * LG) * 8;
  const float* p01 = gp + ((y0 * WG + x1) * LG) * 8;
  const float* p10 = gp + ((y1 * WG + x0) * LG) * 8;
  const float* p11 = gp + ((y1 * WG + x1) * LG) * 8;

  f32x4 s00a = *(const f32x4*)(p00 + z0 * 8), s00b = *(const f32x4*)(p00 + z0 * 8 + 4);
  f32x4 s01a = *(const f32x4*)(p01 + z0 * 8), s01b = *(const f32x4*)(p01 + z0 * 8 + 4);
  f32x4 s10a = *(const f32x4*)(p10 + z0 * 8), s10b = *(const f32x4*)(p10 + z0 * 8 + 4);
  f32x4 s11a = *(const f32x4*)(p11 + z0 * 8), s11b = *(const f32x4*)(p11 + z0 * 8 + 4);
  f32x4 t00a = *(const f32x4*)(p00 + z1 * 8), t00b = *(const f32x4*)(p00 + z1 * 8 + 4);
  f32x4 t01a = *(const f32x4*)(p01 + z1 * 8), t01b = *(const f32x4*)(p01 + z1 * 8 + 4);
  f32x4 t10a = *(const f32x4*)(p10 + z1 * 8), t10b = *(const f32x4*)(p10 + z1 * 8 + 4);
  f32x4 t11a = *(const f32x4*)(p11 + z1 * 8), t11b = *(const f32x4*)(p11 + z1 * 8 + 4);

#pragma unroll
  for (int c = 0; c < 8; ++c) {
    float c00 = (c < 4) ? s00a[c & 3] : s00b[c & 3];
    float c01 = (c < 4) ? s01a[c & 3] : s01b[c & 3];
    float c10 = (c < 4) ? s10a[c & 3] : s10b[c & 3];
    float c11 = (c < 4) ? s11a[c & 3] : s11b[c & 3];
    float d00 = (c < 4) ? t00a[c & 3] : t00b[c & 3];
    float d01 = (c < 4) ? t01a[c & 3] : t01b[c & 3];
    float d10 = (c < 4) ? t10a[c & 3] : t10b[c & 3];
    float d11 = (c < 4) ? t11a[c & 3] : t11b[c & 3];
    float h0 = fmaf(wx, c01 - c00, c00);
    float h1 = fmaf(wx, c11 - c10, c10);
    float v0 = fmaf(wy, h1 - h0, h0);
    float g0v = fmaf(wx, d01 - d00, d00);
    float g1v = fmaf(wx, d11 - d10, d10);
    float v1 = fmaf(wy, g1v - g0v, g0v);
    out8[c] = fmaf(wz, v1 - v0, v0);
  }
}

// ================= main kernel =================
// 1-wave workgroups (waves fully independent: wave-private LDS, no barriers),
// so the SPI backfills residency at wave granularity (r8: occupancy 62% vs 32%).
// launch_bounds(64,4): VGPR budget 128 -- the allocator naturally lands at 64
// (r6 measured); (64,7)'s ~73 cap caused catastrophic spills (r8: WRITE 324MB).
__global__ __launch_bounds__(64, 4) void msnbat_kernel(
    const float* __restrict__ rgb, const void* __restrict__ ws, float* __restrict__ out) {
  __shared__ ushort W[64 * XSTR];  // 4608 B/block
  uint* Wu = (uint*)W;

  const short8* wp = (const short8*)ws;  // frag f, lane l -> wp[f*64+l]
  const float* gp0 = (const float*)((const char*)ws + GP0_OFF);
  const float* gp1 = (const float*)((const char*)ws + GP1_OFF);
  const float* gp2 = (const float*)((const char*)ws + GP2_OFF);

  const int lane = threadIdx.x;
  const int g = lane >> 4, r = lane & 15;
  const int pixbase = blockIdx.x * 64;
  const int p = pixbase + lane;
  const int row = p / W_IMG;
  const int col = p - row * W_IMG;

  const float rr = rgb[p * 3 + 0], gg = rgb[p * 3 + 1], bb = rgb[p * 3 + 2];
  const float gray = fminf(fmaxf(rr * 0.299f + gg * 0.587f + bb * 0.114f, 0.f), 1.f);

  // ---- slice 24 features (lane = its own pixel) ----
  float f[24];
  slice_pack<16, 16, 8>(gp0, row, col, gray, f);
  slice_pack<12, 12, 8>(gp1, row, col, gray, f + 8);
  slice_pack<8, 8, 4>(gp2, row, col, gray, f + 16);

  // ---- stage X: row = pixel(lane), cols 0..23 bf16 feats (24..31 unwritten) ----
  {
    const int ub = lane * 18;  // uint base of this row
#pragma unroll
    for (int i = 0; i < 6; ++i) {
      uint2 v = make_uint2(pkbf(f[4 * i + 0], f[4 * i + 1]), pkbf(f[4 * i + 2], f[4 * i + 3]));
      *(uint2*)&Wu[ub + 2 * i] = v;
    }
  }

  const short8 zero8 = (short8){0, 0, 0, 0, 0, 0, 0, 0};

  // ---- B1 frags: lane(g,r) reads X[pixel r+16nt][feat 8g+j]; g==3 = K-pad -> 0 ----
  short8 B1[4];
#pragma unroll
  for (int nt = 0; nt < 4; ++nt) {
    short4v lo = *(short4v*)&W[(r + 16 * nt) * XSTR + 8 * g];
    short4v hi = *(short4v*)&W[(r + 16 * nt) * XSTR + 8 * g + 4];
    short8 v = __builtin_shufflevector(lo, hi, 0, 1, 2, 3, 4, 5, 6, 7);
    B1[nt] = (g < 3) ? v : zero8;
  }

  // ---- L1 (24->64) in mt-halves; stage tanh(H1) halves; build B2 frags ----
  short8 B2[2][4];
#pragma unroll
  for (int half = 0; half < 2; ++half) {
#pragma unroll
    for (int mtl = 0; mtl < 2; ++mtl) {
      const int mt = 2 * half + mtl;
      short8 A = wp[mt * 64 + lane];
      f32x4 a[4];
#pragma unroll
      for (int nt = 0; nt < 4; ++nt) a[nt] = (f32x4){0.f, 0.f, 0.f, 0.f};
#pragma unroll
      for (int nt = 0; nt < 4; ++nt)
        a[nt] = __builtin_amdgcn_mfma_f32_16x16x32_bf16(A, B1[nt], a[nt], 0, 0, 0);
#pragma unroll
      for (int nt = 0; nt < 4; ++nt) {
        uint2 v = make_uint2(pkbf(tanh5(a[nt][0]), tanh5(a[nt][1])),
                             pkbf(tanh5(a[nt][2]), tanh5(a[nt][3])));
        *(uint2*)&Wu[(16 * nt + r) * 18 + 8 * mtl + 2 * g] = v;
      }
    }
#pragma unroll
    for (int nt = 0; nt < 4; ++nt) {
      short4v lo = *(short4v*)&W[(16 * nt + r) * XSTR + 8 * g];
      short4v hi = *(short4v*)&W[(16 * nt + r) * XSTR + 8 * g + 4];
      B2[half][nt] = __builtin_shufflevector(lo, hi, 0, 1, 2, 3, 4, 5, 6, 7);
    }
  }

  // ---- L2 (64->64) in mt-halves; stage tanh(H2) halves; build B3 frags ----
  short8 B3[2][4];
#pragma unroll
  for (int half = 0; half < 2; ++half) {
#pragma unroll
    for (int mtl = 0; mtl < 2; ++mtl) {
      const int mt = 2 * half + mtl;
      short8 A0 = wp[(4 + mt) * 64 + lane];  // ks=0
      short8 A1 = wp[(8 + mt) * 64 + lane];  // ks=1
      f32x4 a[4];
#pragma unroll
      for (int nt = 0; nt < 4; ++nt) a[nt] = (f32x4){0.f, 0.f, 0.f, 0.f};
#pragma unroll
      for (int nt = 0; nt < 4; ++nt)
        a[nt] = __builtin_amdgcn_mfma_f32_16x16x32_bf16(A0, B2[0][nt], a[nt], 0, 0, 0);
#pragma unroll
      for (int nt = 0; nt < 4; ++nt)
        a[nt] = __builtin_amdgcn_mfma_f32_16x16x32_bf16(A1, B2[1][nt], a[nt], 0, 0, 0);
#pragma unroll
      for (int nt = 0; nt < 4; ++nt) {
        uint2 v = make_uint2(pkbf(tanh5(a[nt][0]), tanh5(a[nt][1])),
                             pkbf(tanh5(a[nt][2]), tanh5(a[nt][3])));
        *(uint2*)&Wu[(16 * nt + r) * 18 + 8 * mtl + 2 * g] = v;
      }
    }
#pragma unroll
    for (int nt = 0; nt < 4; ++nt) {
      short4v lo = *(short4v*)&W[(16 * nt + r) * XSTR + 8 * g];
      short4v hi = *(short4v*)&W[(16 * nt + r) * XSTR + 8 * g + 4];
      B3[half][nt] = __builtin_shufflevector(lo, hi, 0, 1, 2, 3, 4, 5, 6, 7);
    }
  }

  // ---- L3 (64->12): M=16 (12 valid), K=64 ----
  f32x4 acc3[4];
#pragma unroll
  for (int nt = 0; nt < 4; ++nt) acc3[nt] = (f32x4){0.f, 0.f, 0.f, 0.f};
  {
    short8 A0 = wp[12 * 64 + lane];
    short8 A1 = wp[13 * 64 + lane];
#pragma unroll
    for (int nt = 0; nt < 4; ++nt)
      acc3[nt] = __builtin_amdgcn_mfma_f32_16x16x32_bf16(A0, B3[0][nt], acc3[nt], 0, 0, 0);
#pragma unroll
    for (int nt = 0; nt < 4; ++nt)
      acc3[nt] = __builtin_amdgcn_mfma_f32_16x16x32_bf16(A1, B3[1][nt], acc3[nt], 0, 0, 0);
  }

  // ---- store: lane(g<3, r) holds channels 4g..4g+3 of pixel 16nt+r ----
  if (g < 3) {
#pragma unroll
    for (int nt = 0; nt < 4; ++nt) {
      int pix = pixbase + 16 * nt + r;
      *(f32x4*)(out + pix * 12 + 4 * g) = acc3[nt];
    }
  }
}

extern "C" void kernel_launch(void* const* d_in, const int* in_sizes, int n_in,
                              void* d_out, int out_size, void* d_ws, size_t ws_size,
                              hipStream_t stream) {
  const float* rgb = (const float*)d_in[0];
  const float* g0 = (const float*)d_in[1];
  const float* g1 = (const float*)d_in[2];
  const float* g2 = (const float*)d_in[3];
  const float* w1 = (const float*)d_in[4];
  const float* w2 = (const float*)d_in[5];
  const float* w3 = (const float*)d_in[6];
  const int* cam = (const int*)d_in[7];
  float* out = (float*)d_out;

  hipLaunchKernelGGL(prep_kernel, dim3(64), dim3(256), 0, stream,
                     g0, g1, g2, w1, w2, w3, cam, d_ws);
  hipLaunchKernelGGL(msnbat_kernel, dim3(NPIX / 64), dim3(64), 0, stream,
                     rgb, d_ws, out);
}

// Round 11
// 53.776 us; speedup vs baseline: 2.0750x; 1.0875x over previous
//
#include <hip/hip_runtime.h>
#include <hip/hip_bf16.h>

#define H_IMG 720
#define W_IMG 1280
#define NPIX (H_IMG * W_IMG)

typedef __attribute__((ext_vector_type(4))) float f32x4;
typedef __attribute__((ext_vector_type(8))) short short8;
typedef __attribute__((ext_vector_type(4))) short short4v;
typedef __attribute__((ext_vector_type(4))) uint u32x4;
typedef _Float16 h8 __attribute__((ext_vector_type(8)));

// ---- workspace layout (bytes) ----
// wpack: 14 f16 A-frags * 64 lanes * 16B
#define WPACK_BYTES (14 * 64 * 16)
#define GP0_OFF WPACK_BYTES                  // 14336 (16-aligned)
#define GP0_N (16 * 16 * 8 * 8)              // f16 elems, [y][x][z][c]
#define GP1_OFF (GP0_OFF + GP0_N * 2)        // 47104
#define GP1_N (12 * 12 * 8 * 8)
#define GP2_OFF (GP1_OFF + GP1_N * 2)        // 65536
#define GP2_N (8 * 8 * 4 * 8)

#define XSTR 36  // ushorts per staging row: 32 payload + 4 pad

__device__ __forceinline__ uint pkh(float a, float b) {
  // v_cvt_pkrtz_f16_f32: 2 f32 -> packed f16x2, one instruction
  auto t = __builtin_amdgcn_cvt_pkrtz(a, b);  // __fp16 ext_vector(2)
  return __builtin_bit_cast(uint, t);
}

__device__ __forceinline__ float tanh5(float x) {
  // tanh(x) = 1 - 2/(e^{2x}+1); graceful at +-inf, no clamp needed.
  float e2 = __builtin_amdgcn_exp2f(x * 2.885390081777927f);  // e^{2x} via v_exp_f32
  return fmaf(-2.f, __builtin_amdgcn_rcpf(e2 + 1.f), 1.f);
}

// ================= prep kernel =================
__global__ __launch_bounds__(256) void prep_kernel(
    const float* __restrict__ g0, const float* __restrict__ g1, const float* __restrict__ g2,
    const float* __restrict__ w1, const float* __restrict__ w2, const float* __restrict__ w3,
    const int* __restrict__ cam, void* __restrict__ ws) {
  ushort* wpack = (ushort*)ws;
  ushort* gp0 = (ushort*)((char*)ws + GP0_OFF);
  ushort* gp1 = (ushort*)((char*)ws + GP1_OFF);
  ushort* gp2 = (ushort*)((char*)ws + GP2_OFF);
  const int ci = cam[0];
  const int tid = blockIdx.x * 256 + threadIdx.x;
  const int nth = gridDim.x * 256;

  // grids -> [y][x][z][c] f16, selected view only
  for (int e = tid; e < GP0_N; e += nth) {
    int c = e & 7; int t = e >> 3; int z = t & 7; t >>= 3; int x = t & 15; int y = t >> 4;
    _Float16 hv = (_Float16)g0[ci * GP0_N + ((c * 8 + z) * 16 + y) * 16 + x];
    gp0[e] = __builtin_bit_cast(ushort, hv);
  }
  for (int e = tid; e < GP1_N; e += nth) {
    int c = e & 7; int t = e >> 3; int z = t & 7; t >>= 3; int x = t % 12; int y = t / 12;
    _Float16 hv = (_Float16)g1[ci * GP1_N + ((c * 8 + z) * 12 + y) * 12 + x];
    gp1[e] = __builtin_bit_cast(ushort, hv);
  }
  for (int e = tid; e < GP2_N; e += nth) {
    int c = e & 7; int t = e >> 3; int z = t & 3; t >>= 2; int x = t & 7; int y = t >> 3;
    _Float16 hv = (_Float16)g2[ci * GP2_N + ((c * 4 + z) * 8 + y) * 8 + x];
    gp2[e] = __builtin_bit_cast(ushort, hv);
  }

  // weights -> per-lane f16 A-fragments (A = W^T).
  // frag f: 0..3 = L1 (mt), 4..11 = L2 (4+ks*4+mt), 12..13 = L3 (ks).
  for (int fl = tid; fl < 14 * 64; fl += nth) {
    int f = fl >> 6, lane = fl & 63;
    int g = lane >> 4, r = lane & 15;
    ushort* dh = wpack + fl * 8;
#pragma unroll
    for (int j = 0; j < 8; ++j) {
      float v = 0.f;
      if (f < 4) {
        int k = 8 * g + j, n = r + 16 * f;
        if (k < 24) v = w1[k * 64 + n];
      } else if (f < 12) {
        int q = f - 4, ks = q >> 2, mt = q & 3;
        v = w2[(8 * g + j + 32 * ks) * 64 + (r + 16 * mt)];
      } else {
        int ks = f - 12;
        if (r < 12) v = w3[(8 * g + j + 32 * ks) * 12 + r];
      }
      _Float16 hv = (_Float16)v;
      dh[j] = __builtin_bit_cast(ushort, hv);
    }
  }
}

// ================= slicing (packed f16) =================
template <int WG, int HG, int LG>
__device__ __forceinline__ h8 slice_h8(const h8* __restrict__ gp,
                                       int row, int col, float gray) {
  float x = (float)col * ((float)(WG - 1) / (float)(W_IMG - 1));
  float y = (float)row * ((float)(HG - 1) / (float)(H_IMG - 1));
  float z = gray * (float)(LG - 1);
  int x0 = (int)x, y0 = (int)y, z0 = (int)z;
  int x1 = min(x0 + 1, WG - 1), y1 = min(y0 + 1, HG - 1), z1 = min(z0 + 1, LG - 1);
  _Float16 wx = (_Float16)(x - (float)x0);
  _Float16 wy = (_Float16)(y - (float)y0);
  _Float16 wz = (_Float16)(z - (float)z0);
  h8 wx8 = {wx, wx, wx, wx, wx, wx, wx, wx};
  h8 wy8 = {wy, wy, wy, wy, wy, wy, wy, wy};
  h8 wz8 = {wz, wz, wz, wz, wz, wz, wz, wz};

  const h8* p00 = gp + (y0 * WG + x0) * LG;
  const h8* p01 = gp + (y0 * WG + x1) * LG;
  const h8* p10 = gp + (y1 * WG + x0) * LG;
  const h8* p11 = gp + (y1 * WG + x1) * LG;

  h8 a00 = p00[z0], a01 = p01[z0], a10 = p10[z0], a11 = p11[z0];
  h8 b00 = p00[z1], b01 = p01[z1], b10 = p10[z1], b11 = p11[z1];

  h8 xa = a00 + wx8 * (a01 - a00);
  h8 xb = a10 + wx8 * (a11 - a10);
  h8 ya = xa + wy8 * (xb - xa);
  h8 xc = b00 + wx8 * (b01 - b00);
  h8 xd = b10 + wx8 * (b11 - b10);
  h8 yb = xc + wy8 * (xd - xc);
  return ya + wz8 * (yb - ya);
}

// ================= main kernel =================
// 1-wave workgroups; wave-private LDS staging (X -> H1a/H1b -> H2a/H2b reuse
// one 64x36-ushort region); no barriers. f16 datapath end-to-end:
// f16 grids + packed-f16 interp + f16 MFMA (16x16x32_f16, same frag layout).
// launch_bounds(64,4): VGPR budget 128; allocator lands ~64, no spill (r9).
__global__ __launch_bounds__(64, 4) void msnbat_kernel(
    const float* __restrict__ rgb, const void* __restrict__ ws, float* __restrict__ out) {
  __shared__ ushort W[64 * XSTR];  // 4608 B/block
  uint* Wu = (uint*)W;

  const h8* wp = (const h8*)ws;  // A-frag f, lane l -> wp[f*64+l]
  const h8* gp0 = (const h8*)((const char*)ws + GP0_OFF);
  const h8* gp1 = (const h8*)((const char*)ws + GP1_OFF);
  const h8* gp2 = (const h8*)((const char*)ws + GP2_OFF);

  const int lane = threadIdx.x;
  const int g = lane >> 4, r = lane & 15;
  const int pixbase = blockIdx.x * 64;
  const int p = pixbase + lane;
  const int row = p / W_IMG;
  const int col = p - row * W_IMG;

  const float rr = rgb[p * 3 + 0], gg = rgb[p * 3 + 1], bb = rgb[p * 3 + 2];
  const float gray = fminf(fmaxf(rr * 0.299f + gg * 0.587f + bb * 0.114f, 0.f), 1.f);

  // ---- slice 24 features (lane = its own pixel), f16 vectors ----
  h8 f0 = slice_h8<16, 16, 8>(gp0, row, col, gray);
  h8 f1 = slice_h8<12, 12, 8>(gp1, row, col, gray);
  h8 f2 = slice_h8<8, 8, 4>(gp2, row, col, gray);

  // ---- stage X: row = pixel(lane), cols 0..23 f16 feats (24..31 unwritten) ----
  {
    const int ub = lane * 18;  // uint base of this row
    u32x4 u0 = __builtin_bit_cast(u32x4, f0);
    u32x4 u1 = __builtin_bit_cast(u32x4, f1);
    u32x4 u2 = __builtin_bit_cast(u32x4, f2);
    *(uint2*)&Wu[ub + 0] = make_uint2(u0[0], u0[1]);
    *(uint2*)&Wu[ub + 2] = make_uint2(u0[2], u0[3]);
    *(uint2*)&Wu[ub + 4] = make_uint2(u1[0], u1[1]);
    *(uint2*)&Wu[ub + 6] = make_uint2(u1[2], u1[3]);
    *(uint2*)&Wu[ub + 8] = make_uint2(u2[0], u2[1]);
    *(uint2*)&Wu[ub + 10] = make_uint2(u2[2], u2[3]);
  }

  const h8 zero8 = (h8){0, 0, 0, 0, 0, 0, 0, 0};

  // ---- B1 frags: lane(g,r) reads X[pixel r+16nt][feat 8g+j]; g==3 = K-pad -> 0 ----
  h8 B1[4];
#pragma unroll
  for (int nt = 0; nt < 4; ++nt) {
    short4v lo = *(short4v*)&W[(r + 16 * nt) * XSTR + 8 * g];
    short4v hi = *(short4v*)&W[(r + 16 * nt) * XSTR + 8 * g + 4];
    short8 s = __builtin_shufflevector(lo, hi, 0, 1, 2, 3, 4, 5, 6, 7);
    B1[nt] = (g < 3) ? __builtin_bit_cast(h8, s) : zero8;
  }

  // ---- L1 (24->64) in mt-halves; stage tanh(H1) halves; build B2 frags ----
  h8 B2[2][4];
#pragma unroll
  for (int half = 0; half < 2; ++half) {
#pragma unroll
    for (int mtl = 0; mtl < 2; ++mtl) {
      const int mt = 2 * half + mtl;
      h8 A = wp[mt * 64 + lane];
      f32x4 a[4];
#pragma unroll
      for (int nt = 0; nt < 4; ++nt) a[nt] = (f32x4){0.f, 0.f, 0.f, 0.f};
#pragma unroll
      for (int nt = 0; nt < 4; ++nt)
        a[nt] = __builtin_amdgcn_mfma_f32_16x16x32_f16(A, B1[nt], a[nt], 0, 0, 0);
#pragma unroll
      for (int nt = 0; nt < 4; ++nt) {
        uint2 v = make_uint2(pkh(tanh5(a[nt][0]), tanh5(a[nt][1])),
                             pkh(tanh5(a[nt][2]), tanh5(a[nt][3])));
        *(uint2*)&Wu[(16 * nt + r) * 18 + 8 * mtl + 2 * g] = v;
      }
    }
#pragma unroll
    for (int nt = 0; nt < 4; ++nt) {
      short4v lo = *(short4v*)&W[(16 * nt + r) * XSTR + 8 * g];
      short4v hi = *(short4v*)&W[(16 * nt + r) * XSTR + 8 * g + 4];
      short8 s = __builtin_shufflevector(lo, hi, 0, 1, 2, 3, 4, 5, 6, 7);
      B2[half][nt] = __builtin_bit_cast(h8, s);
    }
  }

  // ---- L2 (64->64) in mt-halves; stage tanh(H2) halves; build B3 frags ----
  h8 B3[2][4];
#pragma unroll
  for (int half = 0; half < 2; ++half) {
#pragma unroll
    for (int mtl = 0; mtl < 2; ++mtl) {
      const int mt = 2 * half + mtl;
      h8 A0 = wp[(4 + mt) * 64 + lane];  // ks=0
      h8 A1 = wp[(8 + mt) * 64 + lane];  // ks=1
      f32x4 a[4];
#pragma unroll
      for (int nt = 0; nt < 4; ++nt) a[nt] = (f32x4){0.f, 0.f, 0.f, 0.f};
#pragma unroll
      for (int nt = 0; nt < 4; ++nt)
        a[nt] = __builtin_amdgcn_mfma_f32_16x16x32_f16(A0, B2[0][nt], a[nt], 0, 0, 0);
#pragma unroll
      for (int nt = 0; nt < 4; ++nt)
        a[nt] = __builtin_amdgcn_mfma_f32_16x16x32_f16(A1, B2[1][nt], a[nt], 0, 0, 0);
#pragma unroll
      for (int nt = 0; nt < 4; ++nt) {
        uint2 v = make_uint2(pkh(tanh5(a[nt][0]), tanh5(a[nt][1])),
                             pkh(tanh5(a[nt][2]), tanh5(a[nt][3])));
        *(uint2*)&Wu[(16 * nt + r) * 18 + 8 * mtl + 2 * g] = v;
      }
    }
#pragma unroll
    for (int nt = 0; nt < 4; ++nt) {
      short4v lo = *(short4v*)&W[(16 * nt + r) * XSTR + 8 * g];
      short4v hi = *(short4v*)&W[(16 * nt + r) * XSTR + 8 * g + 4];
      short8 s = __builtin_shufflevector(lo, hi, 0, 1, 2, 3, 4, 5, 6, 7);
      B3[half][nt] = __builtin_bit_cast(h8, s);
    }
  }

  // ---- L3 (64->12): M=16 (12 valid), K=64 ----
  f32x4 acc3[4];
#pragma unroll
  for (int nt = 0; nt < 4; ++nt) acc3[nt] = (f32x4){0.f, 0.f, 0.f, 0.f};
  {
    h8 A0 = wp[12 * 64 + lane];
    h8 A1 = wp[13 * 64 + lane];
#pragma unroll
    for (int nt = 0; nt < 4; ++nt)
      acc3[nt] = __builtin_amdgcn_mfma_f32_16x16x32_f16(A0, B3[0][nt], acc3[nt], 0, 0, 0);
#pragma unroll
    for (int nt = 0; nt < 4; ++nt)
      acc3[nt] = __builtin_amdgcn_mfma_f32_16x16x32_f16(A1, B3[1][nt], acc3[nt], 0, 0, 0);
  }

  // ---- store: lane(g<3, r) holds channels 4g..4g+3 of pixel 16nt+r ----
  if (g < 3) {
#pragma unroll
    for (int nt = 0; nt < 4; ++nt) {
      int pix = pixbase + 16 * nt + r;
      *(f32x4*)(out + pix * 12 + 4 * g) = acc3[nt];
    }
  }
}

extern "C" void kernel_launch(void* const* d_in, const int* in_sizes, int n_in,
                              void* d_out, int out_size, void* d_ws, size_t ws_size,
                              hipStream_t stream) {
  const float* rgb = (const float*)d_in[0];
  const float* g0 = (const float*)d_in[1];
  const float* g1 = (const float*)d_in[2];
  const float* g2 = (const float*)d_in[3];
  const float* w1 = (const float*)d_in[4];
  const float* w2 = (const float*)d_in[5];
  const float* w3 = (const float*)d_in[6];
  const int* cam = (const int*)d_in[7];
  float* out = (float*)d_out;

  hipLaunchKernelGGL(prep_kernel, dim3(64), dim3(256), 0, stream,
                     g0, g1, g2, w1, w2, w3, cam, d_ws);
  hipLaunchKernelGGL(msnbat_kernel, dim3(NPIX / 64), dim3(64), 0, stream,
                     rgb, d_ws, out);
}